// Round 4
// baseline (526.606 us; speedup 1.0000x reference)
//
#include <hip/hip_runtime.h>

#define NTOK 64
#define DIM 192
#define HEADS 6
#define HD 32
#define SCALE 0.17677669529663687f   // 32^-0.5
#define LOG2E 1.4426950408889634f
#define XSS 200                      // xs row stride in ushorts (400 B, 16B-aligned)

typedef __bf16 bf16x8 __attribute__((ext_vector_type(8)));
typedef __bf16 bf16x4 __attribute__((ext_vector_type(4)));
typedef float f32x4 __attribute__((ext_vector_type(4)));

union F4 { float4 v; float f[4]; };

// ---------------- pre-pass: weights -> bf16, bias gather -> dense ----------
// biasf is pre-multiplied by log2(e): softmax runs in exp2 domain.
__global__ void prep_kernel(const float* __restrict__ qkv_w,
                            const float* __restrict__ proj_w,
                            const float* __restrict__ bias_table,
                            const int* __restrict__ rel_idx,
                            unsigned short* __restrict__ wq,
                            unsigned short* __restrict__ wp,
                            float* __restrict__ biasf) {
  int i = blockIdx.x * 256 + threadIdx.x;
  if (i < 3 * DIM * DIM) ((__bf16*)wq)[i] = (__bf16)qkv_w[i];
  if (i < DIM * DIM) ((__bf16*)wp)[i] = (__bf16)proj_w[i];
  if (i < HEADS * NTOK * NTOK) {
    int h = i >> 12;       // 4096 entries per head
    int nm = i & 4095;
    biasf[i] = bias_table[rel_idx[nm] * HEADS + h] * LOG2E;
  }
}

// ---------------- fused window attention: 1 block = 1 window ----------------
// Register-resident pipeline. Only LDS use is the x staging buffer (25.6 KB),
// reused for the attention-output -> proj handoff. Softmax: exp2-domain,
// no max-subtraction (s ~ N(0,1) by construction, |s*log2e| < 9), bias via
// MFMA C-init. P is normalized IN the softmax loop (lane row = 16nt+l15);
// deferring 1/sum to the PV output is WRONG there (output lane row =
// 16nt+quad*4+g != 16nt+l15 — round-3 bug).
//   pi_dt(i) = (i>>2)*8 + 4*dt + (i&3)   (A-row permutation)
__global__ __launch_bounds__(384) void attn_kernel(
    const float* __restrict__ x,
    const float* __restrict__ qkv_b,
    const float* __restrict__ proj_b,
    const unsigned short* __restrict__ wq,
    const unsigned short* __restrict__ wp,
    const float* __restrict__ biasf,
    float* __restrict__ out) {
  __shared__ unsigned short xs[NTOK * XSS];  // 25600 B

  const int tid = threadIdx.x;
  const int w = tid >> 6;       // wave 0..5 == head
  const int lane = tid & 63;
  const int l15 = lane & 15;
  const int quad = lane >> 4;
  const long b = blockIdx.x;
  const int h = w;

  // ---- stage 1: load x (fp32) -> LDS bf16 ----
  {
    const float4* xg = (const float4*)(x + b * (NTOK * DIM));
    #pragma unroll
    for (int it = 0; it < 8; ++it) {
      int idx = tid + it * 384;        // 3072 float4 total
      float4 v = xg[idx];
      int row = idx / 48;
      int col = (idx % 48) * 4;
      bf16x4 o;
      o[0] = (__bf16)v.x; o[1] = (__bf16)v.y;
      o[2] = (__bf16)v.z; o[3] = (__bf16)v.w;
      *(bf16x4*)&xs[row * XSS + col] = o;
    }
  }
  __syncthreads();

  const int prm = ((l15 >> 2) << 3) | (l15 & 3);  // pi_0(l15), pi_1 = prm+4
  const f32x4 zero = {0.f, 0.f, 0.f, 0.f};
  const float qsc = SCALE * LOG2E;   // fold softmax exp2-domain into q scale

  // ---- step A: transposed q GEMM -> qfrag[nt] (lane: q[n=16nt+l15][d=8q+jj])
  bf16x8 qfrag[4];
  {
    const unsigned short* wqh = wq + ((size_t)h * 32) * DIM;
    F4 qb0, qb1;
    qb0.v = *(const float4*)(qkv_b + h * 32 + quad * 8);
    qb1.v = *(const float4*)(qkv_b + h * 32 + quad * 8 + 4);
    float qb0s[4], qb1s[4];
    #pragma unroll
    for (int g = 0; g < 4; ++g) { qb0s[g] = qb0.f[g] * qsc; qb1s[g] = qb1.f[g] * qsc; }
    #pragma unroll
    for (int nt = 0; nt < 4; ++nt) {
      bf16x8 xn[6];
      #pragma unroll
      for (int ks = 0; ks < 6; ++ks)
        xn[ks] = *(const bf16x8*)&xs[(nt * 16 + l15) * XSS + ks * 32 + quad * 8];
      f32x4 a0 = zero, a1 = zero;
      #pragma unroll
      for (int ks = 0; ks < 6; ++ks) {
        bf16x8 w0 = *(const bf16x8*)(wqh + (size_t)(prm + 0) * DIM + ks * 32 + quad * 8);
        bf16x8 w1 = *(const bf16x8*)(wqh + (size_t)(prm + 4) * DIM + ks * 32 + quad * 8);
        a0 = __builtin_amdgcn_mfma_f32_16x16x32_bf16(w0, xn[ks], a0, 0, 0, 0);
        a1 = __builtin_amdgcn_mfma_f32_16x16x32_bf16(w1, xn[ks], a1, 0, 0, 0);
      }
      bf16x8 t;
      #pragma unroll
      for (int g = 0; g < 4; ++g) {
        t[g]     = (__bf16)fmaf(a0[g], qsc, qb0s[g]);
        t[4 + g] = (__bf16)fmaf(a1[g], qsc, qb1s[g]);
      }
      qfrag[nt] = t;
    }
  }

  // ---- steps B+C: transposed k GEMM (permuted m rows) + v GEMM ----
  // kfrag[mt]: lane holds k[m=Rm_mt(l15)][d=8q+jj], Rm_mt(l)=32kv+4half+pi_0(l)
  // vbu[c2][kv]: lane holds v[m=32kv+8q+jj][d=16c2+l15]
  bf16x8 kfrag[4];
  bf16x8 vbu[2][2];
  {
    const unsigned short* wkh = wq + ((size_t)(192 + h * 32)) * DIM;
    const unsigned short* wvh = wq + ((size_t)(384 + h * 32)) * DIM;
    F4 kb0, kb1;
    kb0.v = *(const float4*)(qkv_b + 192 + h * 32 + quad * 8);
    kb1.v = *(const float4*)(qkv_b + 192 + h * 32 + quad * 8 + 4);
    const float vbias0 = qkv_b[384 + h * 32 + l15];
    const float vbias1 = qkv_b[384 + h * 32 + 16 + l15];
    #pragma unroll
    for (int mt = 0; mt < 4; ++mt) {
      const int kv = mt >> 1, half = mt & 1;
      const int xrow = kv * 32 + half * 4 + prm;   // Rm_mt(l15)
      bf16x8 xp[6];
      #pragma unroll
      for (int ks = 0; ks < 6; ++ks)
        xp[ks] = *(const bf16x8*)&xs[xrow * XSS + ks * 32 + quad * 8];
      f32x4 ka0 = zero, ka1 = zero, va0 = zero, va1 = zero;
      #pragma unroll
      for (int ks = 0; ks < 6; ++ks) {
        bf16x8 wk0 = *(const bf16x8*)(wkh + (size_t)(prm + 0) * DIM + ks * 32 + quad * 8);
        bf16x8 wk1 = *(const bf16x8*)(wkh + (size_t)(prm + 4) * DIM + ks * 32 + quad * 8);
        bf16x8 wv0 = *(const bf16x8*)(wvh + (size_t)(l15 + 0) * DIM + ks * 32 + quad * 8);
        bf16x8 wv1 = *(const bf16x8*)(wvh + (size_t)(l15 + 16) * DIM + ks * 32 + quad * 8);
        ka0 = __builtin_amdgcn_mfma_f32_16x16x32_bf16(wk0, xp[ks], ka0, 0, 0, 0);
        ka1 = __builtin_amdgcn_mfma_f32_16x16x32_bf16(wk1, xp[ks], ka1, 0, 0, 0);
        va0 = __builtin_amdgcn_mfma_f32_16x16x32_bf16(xp[ks], wv0, va0, 0, 0, 0);
        va1 = __builtin_amdgcn_mfma_f32_16x16x32_bf16(xp[ks], wv1, va1, 0, 0, 0);
      }
      bf16x8 t;
      #pragma unroll
      for (int g = 0; g < 4; ++g) {
        t[g]     = (__bf16)(ka0[g] + kb0.f[g]);
        t[4 + g] = (__bf16)(ka1[g] + kb1.f[g]);
        vbu[0][kv][half * 4 + g] = (__bf16)(va0[g] + vbias0);
        vbu[1][kv][half * 4 + g] = (__bf16)(va1[g] + vbias1);
      }
      kfrag[mt] = t;
    }
  }

  // ---- stage 3: swapped S GEMM with bias C-init, exp2 softmax, PV ----
  // s[mt][nt][g] = S[n=16nt+l15][m = 32kv + 8q + 4half + g]  (log2-domain)
  const float* bh = biasf + h * 4096;
  f32x4 s[4][4];
  #pragma unroll
  for (int mt = 0; mt < 4; ++mt)
    #pragma unroll
    for (int nt = 0; nt < 4; ++nt) {
      f32x4 binit = *(const f32x4*)(bh + (nt * 16 + l15) * 64 +
                                    (mt >> 1) * 32 + quad * 8 + (mt & 1) * 4);
      s[mt][nt] = __builtin_amdgcn_mfma_f32_16x16x32_bf16(kfrag[mt], qfrag[nt], binit, 0, 0, 0);
    }

  bf16x8 pa[4][2];   // lane: P[n=16nt+l15][m=32kv+8q+jj]
  #pragma unroll
  for (int nt = 0; nt < 4; ++nt) {
    float p[16];
    #pragma unroll
    for (int t = 0; t < 16; ++t)
      p[t] = __builtin_amdgcn_exp2f(s[t >> 2][nt][t & 3]);
    float s0 = (p[0] + p[1]) + (p[2] + p[3]);
    float s1 = (p[4] + p[5]) + (p[6] + p[7]);
    float s2 = (p[8] + p[9]) + (p[10] + p[11]);
    float s3 = (p[12] + p[13]) + (p[14] + p[15]);
    float sm = (s0 + s1) + (s2 + s3);
    sm += __shfl_xor(sm, 16);
    sm += __shfl_xor(sm, 32);
    float r = __builtin_amdgcn_rcpf(sm);
    bf16x8 t0, t1;
    #pragma unroll
    for (int j = 0; j < 8; ++j) {
      t0[j] = (__bf16)(p[j] * r);
      t1[j] = (__bf16)(p[8 + j] * r);
    }
    pa[nt][0] = t0;
    pa[nt][1] = t1;
  }

  f32x4 o[4][2];
  #pragma unroll
  for (int nt = 0; nt < 4; ++nt)
    #pragma unroll
    for (int c2 = 0; c2 < 2; ++c2) {
      f32x4 acc = __builtin_amdgcn_mfma_f32_16x16x32_bf16(pa[nt][0], vbu[c2][0], zero, 0, 0, 0);
      o[nt][c2] = __builtin_amdgcn_mfma_f32_16x16x32_bf16(pa[nt][1], vbu[c2][1], acc, 0, 0, 0);
    }

  // wait until every wave is done reading xs, then overwrite it with attn-out
  __syncthreads();
  #pragma unroll
  for (int nt = 0; nt < 4; ++nt)
    #pragma unroll
    for (int c2 = 0; c2 < 2; ++c2)
      #pragma unroll
      for (int g = 0; g < 4; ++g)
        *(__bf16*)&xs[(nt * 16 + quad * 4 + g) * XSS + h * 32 + c2 * 16 + l15] =
            (__bf16)o[nt][c2][g];
  __syncthreads();

  // ---- stage 4: proj GEMM  out[n][e] = sum_f a[n][f] Wp[e][f] + pb[e] ----
  {
    bf16x8 af[4][6];
    #pragma unroll
    for (int nt = 0; nt < 4; ++nt)
      #pragma unroll
      for (int ks = 0; ks < 6; ++ks)
        af[nt][ks] = *(const bf16x8*)&xs[(nt * 16 + l15) * XSS + ks * 32 + quad * 8];
    float* og = out + b * (NTOK * DIM);
    #pragma unroll
    for (int i = 0; i < 2; ++i) {
      const int e = w * 32 + i * 16 + l15;
      f32x4 acc[4] = {zero, zero, zero, zero};
      #pragma unroll
      for (int ks = 0; ks < 6; ++ks) {
        bf16x8 bw = *(const bf16x8*)(wp + (size_t)e * DIM + ks * 32 + quad * 8);
        #pragma unroll
        for (int nt = 0; nt < 4; ++nt)
          acc[nt] = __builtin_amdgcn_mfma_f32_16x16x32_bf16(af[nt][ks], bw, acc[nt], 0, 0, 0);
      }
      const float pb = proj_b[e];
      #pragma unroll
      for (int nt = 0; nt < 4; ++nt)
        #pragma unroll
        for (int g = 0; g < 4; ++g)
          og[(nt * 16 + quad * 4 + g) * DIM + e] = acc[nt][g] + pb;
    }
  }
}

extern "C" void kernel_launch(void* const* d_in, const int* in_sizes, int n_in,
                              void* d_out, int out_size, void* d_ws, size_t ws_size,
                              hipStream_t stream) {
  const float* x          = (const float*)d_in[0];
  const float* qkv_w      = (const float*)d_in[1];
  const float* qkv_b      = (const float*)d_in[2];
  const float* proj_w     = (const float*)d_in[3];
  const float* proj_b     = (const float*)d_in[4];
  const float* bias_table = (const float*)d_in[5];
  const int*   rel_idx    = (const int*)d_in[6];

  unsigned short* wq = (unsigned short*)d_ws;            // 110592 bf16
  unsigned short* wp = wq + 3 * DIM * DIM;               // 36864 bf16
  float* biasf = (float*)(wp + DIM * DIM);               // 24576 fp32

  prep_kernel<<<432, 256, 0, stream>>>(qkv_w, proj_w, bias_table, rel_idx, wq, wp, biasf);
  attn_kernel<<<4096, 384, 0, stream>>>(x, qkv_b, proj_b, wq, wp, biasf, (float*)d_out);
}

// Round 5
// 474.803 us; speedup vs baseline: 1.1091x; 1.1091x over previous
//
#include <hip/hip_runtime.h>

#define NTOK 64
#define DIM 192
#define HEADS 6
#define HD 32
#define SCALE 0.17677669529663687f   // 32^-0.5
#define LOG2E 1.4426950408889634f
#define XSS 200                      // xs row stride in ushorts (400 B, 16B-aligned)

typedef __bf16 bf16x8 __attribute__((ext_vector_type(8)));
typedef __bf16 bf16x4 __attribute__((ext_vector_type(4)));
typedef float f32x4 __attribute__((ext_vector_type(4)));

union F4 { float4 v; float f[4]; };

// ---------------- pre-pass: weights -> bf16, bias gather -> dense ----------
// biasf is pre-multiplied by log2(e): softmax runs in exp2 domain.
__global__ void prep_kernel(const float* __restrict__ qkv_w,
                            const float* __restrict__ proj_w,
                            const float* __restrict__ bias_table,
                            const int* __restrict__ rel_idx,
                            unsigned short* __restrict__ wq,
                            unsigned short* __restrict__ wp,
                            float* __restrict__ biasf) {
  int i = blockIdx.x * 256 + threadIdx.x;
  if (i < 3 * DIM * DIM) ((__bf16*)wq)[i] = (__bf16)qkv_w[i];
  if (i < DIM * DIM) ((__bf16*)wp)[i] = (__bf16)proj_w[i];
  if (i < HEADS * NTOK * NTOK) {
    int h = i >> 12;       // 4096 entries per head
    int nm = i & 4095;
    biasf[i] = bias_table[rel_idx[nm] * HEADS + h] * LOG2E;
  }
}

// ---------------- fused window attention: 1 block = 2 windows ---------------
// Latency-bound (rocprof r4: MfmaUtil 12, VALUBusy 15, ~73% no-issue; ~1
// block/CU effective residency). Fix: process TWO windows per wave with the
// win loop unrolled inside every stage — win1's independent chains fill
// win0's stalls (in-order issue -> interleave must be textual). Weight and
// bias fragments are window-invariant: loaded once, used twice.
//   pi_dt(i) = (i>>2)*8 + 4*dt + (i&3)   (A-row permutation)
__global__ __launch_bounds__(384) void attn_kernel(
    const float* __restrict__ x,
    const float* __restrict__ qkv_b,
    const float* __restrict__ proj_b,
    const unsigned short* __restrict__ wq,
    const unsigned short* __restrict__ wp,
    const float* __restrict__ biasf,
    float* __restrict__ out) {
  __shared__ unsigned short xs[2][NTOK * XSS];  // 51200 B

  const int tid = threadIdx.x;
  const int w = tid >> 6;       // wave 0..5 == head
  const int lane = tid & 63;
  const int l15 = lane & 15;
  const int quad = lane >> 4;
  const long b0 = (long)blockIdx.x * 2;
  const int h = w;

  // ---- stage 1: load x (fp32) for both windows -> LDS bf16 ----
  {
    const float4* xg = (const float4*)(x + b0 * (NTOK * DIM));  // 6144 float4
    #pragma unroll
    for (int it = 0; it < 16; ++it) {
      int win = it >> 3;
      int idx = tid + it * 384;
      int r = idx - win * 3072;
      float4 v = xg[idx];
      int row = r / 48;
      int col = (r % 48) * 4;
      bf16x4 o;
      o[0] = (__bf16)v.x; o[1] = (__bf16)v.y;
      o[2] = (__bf16)v.z; o[3] = (__bf16)v.w;
      *(bf16x4*)&xs[win][row * XSS + col] = o;
    }
  }
  __syncthreads();

  const int prm = ((l15 >> 2) << 3) | (l15 & 3);  // pi_0(l15), pi_1 = prm+4
  const f32x4 zero = {0.f, 0.f, 0.f, 0.f};
  const float qsc = SCALE * LOG2E;   // fold softmax exp2-domain into q scale

  // ---- step A: transposed q GEMM -> qfrag[win][nt] (q[n=16nt+l15][d=8q+jj])
  bf16x8 qfrag[2][4];
  {
    const unsigned short* wqh = wq + ((size_t)h * 32) * DIM;
    F4 qb0, qb1;
    qb0.v = *(const float4*)(qkv_b + h * 32 + quad * 8);
    qb1.v = *(const float4*)(qkv_b + h * 32 + quad * 8 + 4);
    float qb0s[4], qb1s[4];
    #pragma unroll
    for (int g = 0; g < 4; ++g) { qb0s[g] = qb0.f[g] * qsc; qb1s[g] = qb1.f[g] * qsc; }
    #pragma unroll
    for (int nt = 0; nt < 4; ++nt) {
      f32x4 a0[2] = {zero, zero}, a1[2] = {zero, zero};
      #pragma unroll
      for (int ks = 0; ks < 6; ++ks) {
        bf16x8 w0 = *(const bf16x8*)(wqh + (size_t)(prm + 0) * DIM + ks * 32 + quad * 8);
        bf16x8 w1 = *(const bf16x8*)(wqh + (size_t)(prm + 4) * DIM + ks * 32 + quad * 8);
        #pragma unroll
        for (int win = 0; win < 2; ++win) {
          bf16x8 xn = *(const bf16x8*)&xs[win][(nt * 16 + l15) * XSS + ks * 32 + quad * 8];
          a0[win] = __builtin_amdgcn_mfma_f32_16x16x32_bf16(w0, xn, a0[win], 0, 0, 0);
          a1[win] = __builtin_amdgcn_mfma_f32_16x16x32_bf16(w1, xn, a1[win], 0, 0, 0);
        }
      }
      #pragma unroll
      for (int win = 0; win < 2; ++win) {
        bf16x8 t;
        #pragma unroll
        for (int g = 0; g < 4; ++g) {
          t[g]     = (__bf16)fmaf(a0[win][g], qsc, qb0s[g]);
          t[4 + g] = (__bf16)fmaf(a1[win][g], qsc, qb1s[g]);
        }
        qfrag[win][nt] = t;
      }
    }
  }

  // ---- steps B+C: transposed k GEMM (permuted m rows) + v GEMM ----
  // kfrag[win][mt]: k[m=Rm_mt(l15)][d=8q+jj], Rm_mt(l)=32kv+4half+pi_0(l)
  // vbu[win][c2][kv]: v[m=32kv+8q+jj][d=16c2+l15]
  bf16x8 kfrag[2][4];
  bf16x8 vbu[2][2][2];
  {
    const unsigned short* wkh = wq + ((size_t)(192 + h * 32)) * DIM;
    const unsigned short* wvh = wq + ((size_t)(384 + h * 32)) * DIM;
    F4 kb0, kb1;
    kb0.v = *(const float4*)(qkv_b + 192 + h * 32 + quad * 8);
    kb1.v = *(const float4*)(qkv_b + 192 + h * 32 + quad * 8 + 4);
    const float vbias0 = qkv_b[384 + h * 32 + l15];
    const float vbias1 = qkv_b[384 + h * 32 + 16 + l15];
    #pragma unroll
    for (int mt = 0; mt < 4; ++mt) {
      const int kv = mt >> 1, half = mt & 1;
      const int xrow = kv * 32 + half * 4 + prm;   // Rm_mt(l15)
      f32x4 ka0[2] = {zero, zero}, ka1[2] = {zero, zero};
      f32x4 va0[2] = {zero, zero}, va1[2] = {zero, zero};
      #pragma unroll
      for (int ks = 0; ks < 6; ++ks) {
        bf16x8 wk0 = *(const bf16x8*)(wkh + (size_t)(prm + 0) * DIM + ks * 32 + quad * 8);
        bf16x8 wk1 = *(const bf16x8*)(wkh + (size_t)(prm + 4) * DIM + ks * 32 + quad * 8);
        bf16x8 wv0 = *(const bf16x8*)(wvh + (size_t)(l15 + 0) * DIM + ks * 32 + quad * 8);
        bf16x8 wv1 = *(const bf16x8*)(wvh + (size_t)(l15 + 16) * DIM + ks * 32 + quad * 8);
        #pragma unroll
        for (int win = 0; win < 2; ++win) {
          bf16x8 xp = *(const bf16x8*)&xs[win][xrow * XSS + ks * 32 + quad * 8];
          ka0[win] = __builtin_amdgcn_mfma_f32_16x16x32_bf16(wk0, xp, ka0[win], 0, 0, 0);
          ka1[win] = __builtin_amdgcn_mfma_f32_16x16x32_bf16(wk1, xp, ka1[win], 0, 0, 0);
          va0[win] = __builtin_amdgcn_mfma_f32_16x16x32_bf16(xp, wv0, va0[win], 0, 0, 0);
          va1[win] = __builtin_amdgcn_mfma_f32_16x16x32_bf16(xp, wv1, va1[win], 0, 0, 0);
        }
      }
      #pragma unroll
      for (int win = 0; win < 2; ++win) {
        bf16x8 t;
        #pragma unroll
        for (int g = 0; g < 4; ++g) {
          t[g]     = (__bf16)(ka0[win][g] + kb0.f[g]);
          t[4 + g] = (__bf16)(ka1[win][g] + kb1.f[g]);
          vbu[win][0][kv][half * 4 + g] = (__bf16)(va0[win][g] + vbias0);
          vbu[win][1][kv][half * 4 + g] = (__bf16)(va1[win][g] + vbias1);
        }
        kfrag[win][mt] = t;
      }
    }
  }

  // ---- stage 3: S GEMM (bias C-init, shared across wins) + exp2 softmax ----
  // sv[mt][g] = S[n=16nt+l15][m = 32kv + 8q + 4half + g]  (log2-domain)
  const float* bh = biasf + h * 4096;
  bf16x8 pa[2][4][2];   // P[n=16nt+l15][m=32kv+8q+jj]
  #pragma unroll
  for (int nt = 0; nt < 4; ++nt) {
    f32x4 binit[4];
    #pragma unroll
    for (int mt = 0; mt < 4; ++mt)
      binit[mt] = *(const f32x4*)(bh + (nt * 16 + l15) * 64 +
                                  (mt >> 1) * 32 + quad * 8 + (mt & 1) * 4);
    #pragma unroll
    for (int win = 0; win < 2; ++win) {
      f32x4 sv[4];
      #pragma unroll
      for (int mt = 0; mt < 4; ++mt)
        sv[mt] = __builtin_amdgcn_mfma_f32_16x16x32_bf16(kfrag[win][mt], qfrag[win][nt],
                                                         binit[mt], 0, 0, 0);
      float p[16];
      #pragma unroll
      for (int t = 0; t < 16; ++t)
        p[t] = __builtin_amdgcn_exp2f(sv[t >> 2][t & 3]);
      float s0 = (p[0] + p[1]) + (p[2] + p[3]);
      float s1 = (p[4] + p[5]) + (p[6] + p[7]);
      float s2 = (p[8] + p[9]) + (p[10] + p[11]);
      float s3 = (p[12] + p[13]) + (p[14] + p[15]);
      float sm = (s0 + s1) + (s2 + s3);
      sm += __shfl_xor(sm, 16);
      sm += __shfl_xor(sm, 32);
      float r = __builtin_amdgcn_rcpf(sm);
      bf16x8 t0, t1;
      #pragma unroll
      for (int j = 0; j < 8; ++j) {
        t0[j] = (__bf16)(p[j] * r);
        t1[j] = (__bf16)(p[8 + j] * r);
      }
      pa[win][nt][0] = t0;
      pa[win][nt][1] = t1;
    }
  }

  // ---- PV ----
  f32x4 o[2][4][2];
  #pragma unroll
  for (int nt = 0; nt < 4; ++nt)
    #pragma unroll
    for (int win = 0; win < 2; ++win)
      #pragma unroll
      for (int c2 = 0; c2 < 2; ++c2) {
        f32x4 acc = __builtin_amdgcn_mfma_f32_16x16x32_bf16(pa[win][nt][0], vbu[win][c2][0],
                                                            zero, 0, 0, 0);
        o[win][nt][c2] = __builtin_amdgcn_mfma_f32_16x16x32_bf16(pa[win][nt][1], vbu[win][c2][1],
                                                                 acc, 0, 0, 0);
      }

  // wait until every wave is done reading xs, then overwrite with attn-out
  __syncthreads();
  #pragma unroll
  for (int win = 0; win < 2; ++win)
    #pragma unroll
    for (int nt = 0; nt < 4; ++nt)
      #pragma unroll
      for (int c2 = 0; c2 < 2; ++c2)
        #pragma unroll
        for (int g = 0; g < 4; ++g)
          *(__bf16*)&xs[win][(nt * 16 + quad * 4 + g) * XSS + h * 32 + c2 * 16 + l15] =
              (__bf16)o[win][nt][c2][g];
  __syncthreads();

  // ---- stage 4: proj GEMM  out[n][e] = sum_f a[n][f] Wp[e][f] + pb[e] ----
  #pragma unroll
  for (int i = 0; i < 2; ++i) {
    const int e = w * 32 + i * 16 + l15;
    f32x4 acc[2][4] = {{zero, zero, zero, zero}, {zero, zero, zero, zero}};
    #pragma unroll
    for (int ks = 0; ks < 6; ++ks) {
      bf16x8 bw = *(const bf16x8*)(wp + (size_t)e * DIM + ks * 32 + quad * 8);
      #pragma unroll
      for (int win = 0; win < 2; ++win)
        #pragma unroll
        for (int nt = 0; nt < 4; ++nt) {
          bf16x8 a = *(const bf16x8*)&xs[win][(nt * 16 + l15) * XSS + ks * 32 + quad * 8];
          acc[win][nt] = __builtin_amdgcn_mfma_f32_16x16x32_bf16(a, bw, acc[win][nt], 0, 0, 0);
        }
    }
    const float pb = proj_b[e];
    #pragma unroll
    for (int win = 0; win < 2; ++win) {
      float* og = out + (b0 + win) * (NTOK * DIM);
      #pragma unroll
      for (int nt = 0; nt < 4; ++nt)
        #pragma unroll
        for (int g = 0; g < 4; ++g)
          og[(nt * 16 + quad * 4 + g) * DIM + e] = acc[win][nt][g] + pb;
    }
  }
}

extern "C" void kernel_launch(void* const* d_in, const int* in_sizes, int n_in,
                              void* d_out, int out_size, void* d_ws, size_t ws_size,
                              hipStream_t stream) {
  const float* x          = (const float*)d_in[0];
  const float* qkv_w      = (const float*)d_in[1];
  const float* qkv_b      = (const float*)d_in[2];
  const float* proj_w     = (const float*)d_in[3];
  const float* proj_b     = (const float*)d_in[4];
  const float* bias_table = (const float*)d_in[5];
  const int*   rel_idx    = (const int*)d_in[6];

  unsigned short* wq = (unsigned short*)d_ws;            // 110592 bf16
  unsigned short* wp = wq + 3 * DIM * DIM;               // 36864 bf16
  float* biasf = (float*)(wp + DIM * DIM);               // 24576 fp32

  prep_kernel<<<432, 256, 0, stream>>>(qkv_w, proj_w, bias_table, rel_idx, wq, wp, biasf);
  attn_kernel<<<2048, 384, 0, stream>>>(x, qkv_b, proj_b, wq, wp, biasf, (float*)d_out);
}